// Round 9
// baseline (30.934 us; speedup 1.0000x reference)
//
#include <hip/hip_runtime.h>
#include <math.h>

#define NCLS 80
#define NA 5
#define NH 32
#define NW 32
#define TBX 50            // MAX_BOXES
#define CH (5 + NCLS)     // 85 channels per anchor
#define QPIX 256          // pixels per block (quarter of 32x32)

__device__ __forceinline__ float sigm(float z) { return 1.0f / (1.0f + expf(-z)); }

// matches reference: -(t*clip(log p,-100) + (1-t)*clip(log1p(-p),-100))
__device__ __forceinline__ float bce(float p, float t) {
    float lp  = fmaxf(logf(p), -100.0f);
    float l1p = fmaxf(log1pf(-p), -100.0f);
    return -(t * lp + (1.0f - t) * l1p);
}

__global__ __launch_bounds__(256) void yolo_loss_kernel(
    const float* __restrict__ outp, const float* __restrict__ target,
    float* __restrict__ partials,
    unsigned* __restrict__ ctr,      // memset to 0 by the preceding graph node
    float* __restrict__ out,
    int nblk, float inv_nB)
{
    const int blk = blockIdx.x;        // ((b*NA)+A)*4 + q
    const int q   = blk & 3;
    const int bA  = blk >> 2;
    const int b   = bA / NA;
    const int A   = bA - b * NA;
    const int tid = threadIdx.x;

    // issue the conf-plane load FIRST: its HBM latency hides under all the
    // metadata/scatter work below.
    const float* base = outp + ((size_t)b * (NA * CH) + (size_t)A * CH) * (NH * NW)
                        + (size_t)q * QPIX;       // base[c*1024 + p], p in [0,256)
    const float conf = base[4 * 1024 + tid];

    __shared__ float s_tx[TBX], s_ty[TBX], s_tw[TBX], s_th[TBX];
    __shared__ unsigned char s_valid[TBX];
    __shared__ int      winner[QPIX];          // last matched box idx per cell (-1 none)
    __shared__ unsigned clsm[QPIX][3];         // 80-bit class union per cell
    __shared__ unsigned clearbits[QPIX / 32];  // 8 words
    __shared__ unsigned objbits[QPIX / 32];
    __shared__ int   objlist[TBX];
    __shared__ float s_part[4];
    __shared__ int   s_trigger;

    // ---- init LDS grids ----
    winner[tid] = -1;
    clsm[tid][0] = 0; clsm[tid][1] = 0; clsm[tid][2] = 0;
    if (tid < QPIX / 32) { clearbits[tid] = 0; objbits[tid] = 0; }

    // ---- phase 1: per-box metadata, all in registers (wave 0 only) ----
    const bool active = tid < TBX;
    int  cell = 0, cls = 0;
    bool match = false, clearb = false, v = false;
    if (active) {
        const float* tg = target + (size_t)b * TBX * 5 + tid * 5;
        float clsf = tg[0];
        float xx = tg[1], yy = tg[2], ww = tg[3], hh = tg[4];
        float gx = xx * NW, gy = yy * NH, gw = ww * NW, gh = hh * NH;
        int gi = (int)gx; gi = min(max(gi, 0), NW - 1);  // trunc == astype(int32)
        int gj = (int)gy; gj = min(max(gj, 0), NH - 1);
        const float AW[NA] = {1.3125f, 3.1875f, 5.03125f, 9.46875f, 11.21875f};
        const float AH[NA] = {1.71875f, 4.0f,   8.09375f, 4.84375f, 10.0f};
        int best = 0; float bi = -1.0f, bw = 0.f, bh = 0.f, iouA = 0.f;
        #pragma unroll
        for (int a = 0; a < NA; ++a) {
            float aw = AW[a], ah = AH[a];
            float inter = fmaxf(fminf(gw, aw) + 1.0f, 0.0f) * fmaxf(fminf(gh, ah) + 1.0f, 0.0f);
            float iou = inter / ((gw + 1.0f) * (gh + 1.0f) + (aw + 1.0f) * (ah + 1.0f) - inter + 1e-16f);
            if (iou > bi) { bi = iou; best = a; bw = aw; bh = ah; }   // first max wins
            if (a == A) iouA = iou;
        }
        cell   = gj * NW + gi;
        match  = (best == A);
        clearb = (iouA > 0.6f) || match;
        cls = (int)clsf; cls = min(max(cls, 0), NCLS - 1);
        // validity = cumprod(x != 0) via one ballot (lanes 0..49 in wave 0)
        unsigned long long m = __ballot(xx != 0.0f);
        v = (((~m) & ((1ULL << (tid + 1)) - 1ULL)) == 0ULL);
        s_valid[tid] = v ? 1 : 0;
        s_tx[tid] = gx - (float)gi;
        s_ty[tid] = gy - (float)gj;
        s_tw[tid] = logf(fmaxf(gw, 1e-8f) / bw);
        s_th[tid] = logf(fmaxf(gh, 1e-8f) / bh);
    }
    __syncthreads();   // LDS-grid init visible

    // ---- phase 2: scatter into LDS grids (registers carried across sync) ----
    if (active && (cell >> 8) == q) {            // cell lies in this block's quarter
        int p = cell & (QPIX - 1);
        if (clearb && v) atomicOr(&clearbits[p >> 5], 1u << (p & 31));
        if (match) {
            atomicMax(&winner[p], tid);          // .set last-write-wins == max box idx
            if (v) {
                atomicOr(&objbits[p >> 5], 1u << (p & 31));
                atomicOr(&clsm[p][cls >> 5], 1u << (cls & 31));
            }
        }
    }
    __syncthreads();

    // ---- phase 3: one pixel per thread; deterministic popcount-rank objlist ----
    float lsum = 0.0f;
    const int p = tid;
    const unsigned ow = objbits[p >> 5];
    const unsigned objb = (ow >> (p & 31)) & 1u;
    const unsigned clrb = (clearbits[p >> 5] >> (p & 31)) & 1u;
    if (objb) {
        int rank = __popc(ow & ((1u << (p & 31)) - 1u));
        for (int k = 0; k < (p >> 5); ++k) rank += __popc(objbits[k]);
        objlist[rank] = p;
    } else if (!clrb) {
        // noobj cell: conf channel only (value already in register)
        lsum += -0.5f * fmaxf(log1pf(-sigm(conf)), -100.0f);  // 0.5*bce(conf,0)
    }
    int nobj = 0;
    #pragma unroll
    for (int k = 0; k < QPIX / 32; ++k) nobj += __popc(objbits[k]);
    __syncthreads();   // objlist visible

    // ---- phase 4: obj cells flattened into nobj*85 parallel work items ----
    const int total = nobj * CH;
    for (int idx = tid; idx < total; idx += 256) {
        int e = idx / CH;               // const-85 division -> magic mul
        int c = idx - e * CH;
        int pc = objlist[e];
        float oc = base[c * 1024 + pc];
        int w = winner[pc];
        bool wv = s_valid[w] != 0;      // invalid winner => targets are 0
        float contrib;
        if (c == 0)      contrib = bce(sigm(oc), wv ? s_tx[w] : 0.0f);
        else if (c == 1) contrib = bce(sigm(oc), wv ? s_ty[w] : 0.0f);
        else if (c == 2) { float d = oc - (wv ? s_tw[w] : 0.0f); contrib = d * d; }
        else if (c == 3) { float d = oc - (wv ? s_th[w] : 0.0f); contrib = d * d; }
        else if (c == 4) contrib = -fmaxf(logf(sigm(oc)), -100.0f);  // bce(conf,1)
        else {
            int cc = c - 5;
            unsigned bit = (clsm[pc][cc >> 5] >> (cc & 31)) & 1u;
            contrib = bce(sigm(oc), bit ? 1.0f : 0.0f);
        }
        lsum += contrib;
    }

    // ---- block reduce: wave64 shuffle + LDS across 4 waves ----
    #pragma unroll
    for (int off = 32; off > 0; off >>= 1)
        lsum += __shfl_down(lsum, off, 64);
    if ((tid & 63) == 0) s_part[tid >> 6] = lsum;
    __syncthreads();

    // ---- EXACT arrive-last (R6/R7 lesson: modulo trigger on an un-zeroed
    // counter fires at an arbitrary arrival position; the memset node zeroes
    // ctr every call, so old == nblk-1 identifies the true last arrival).
    // All cross-block traffic is RMW-only (R1-proven coherent cross-XCD):
    // publish via atomicExch with the return value consumed (orders it before
    // the counter RMW); trigger reads partials via atomicAdd(p, 0.0f).
    // Partials are distinct addresses -> no same-address burst (R8 lesson).
    if (tid == 0) {
        float part = s_part[0] + s_part[1] + s_part[2] + s_part[3];
        float oldp = atomicExch(&partials[blk], part);
        asm volatile("" :: "v"(oldp) : "memory");   // consume: vmcnt wait + no reorder
        unsigned old = atomicAdd(ctr, 1u);
        s_trigger = (old == (unsigned)(nblk - 1)) ? 1 : 0;
    }
    __syncthreads();

    // ---- last-arriving block reduces all partials inline (RMW reads);
    // summation order identical to R4's reduce_kernel -> bit-identical out.
    if (s_trigger) {
        float s = 0.0f;
        for (int i = tid; i < nblk; i += 256)
            s += atomicAdd(&partials[i], 0.0f);   // RMW read at coherence point
        #pragma unroll
        for (int off = 32; off > 0; off >>= 1)
            s += __shfl_down(s, off, 64);
        if ((tid & 63) == 0) s_part[tid >> 6] = s;
        __syncthreads();
        if (tid == 0)
            out[0] = (s_part[0] + s_part[1] + s_part[2] + s_part[3]) * inv_nB;
    }
}

extern "C" void kernel_launch(void* const* d_in, const int* in_sizes, int n_in,
                              void* d_out, int out_size, void* d_ws, size_t ws_size,
                              hipStream_t stream) {
    const float* outp   = (const float*)d_in[0];
    const float* target = (const float*)d_in[1];
    float* loss = (float*)d_out;
    int nB = in_sizes[1] / (TBX * 5);   // 64
    int nblk = nB * NA * 4;             // 1280

    // d_ws layout: partials[nblk] f32 | (64B-aligned) u32 arrival counter.
    // partials need no init (every slot atomicExch'd before any read);
    // the counter is zeroed each call by the tiny memset node below.
    char* ws = (char*)d_ws;
    float* partials = (float*)ws;
    size_t off = ((size_t)nblk * sizeof(float) + 63) & ~(size_t)63;
    unsigned* ctr = (unsigned*)(ws + off);

    hipMemsetAsync(ctr, 0, sizeof(unsigned), stream);   // ~3 us tiny node (R8-measured)
    yolo_loss_kernel<<<nblk, 256, 0, stream>>>(
        outp, target, partials, ctr, loss, nblk, 1.0f / (float)nB);
}

// Round 10
// 30.605 us; speedup vs baseline: 1.0108x; 1.0108x over previous
//
#include <hip/hip_runtime.h>
#include <math.h>

#define NCLS 80
#define NA 5
#define NH 32
#define NW 32
#define TBX 50            // MAX_BOXES
#define CH (5 + NCLS)     // 85 channels per anchor
#define QPIX 256          // pixels per block (quarter of 32x32)

__device__ __forceinline__ float sigm(float z) { return 1.0f / (1.0f + expf(-z)); }

// matches reference: -(t*clip(log p,-100) + (1-t)*clip(log1p(-p),-100))
__device__ __forceinline__ float bce(float p, float t) {
    float lp  = fmaxf(logf(p), -100.0f);
    float l1p = fmaxf(log1pf(-p), -100.0f);
    return -(t * lp + (1.0f - t) * l1p);
}

// 1-thread counter zero: kernel dispatch path, NOT the blit/fill path —
// hipMemsetAsync's fillBufferAligned costs ~11 us fixed (R8/R9 measured).
__global__ void zero_ctr_kernel(unsigned* ctr) { *ctr = 0u; }

__global__ __launch_bounds__(256) void yolo_loss_kernel(
    const float* __restrict__ outp, const float* __restrict__ target,
    float* __restrict__ partials,
    unsigned* __restrict__ ctr,      // zeroed by zero_ctr_kernel each call
    float* __restrict__ out,
    int nblk, float inv_nB)
{
    const int blk = blockIdx.x;        // ((b*NA)+A)*4 + q
    const int q   = blk & 3;
    const int bA  = blk >> 2;
    const int b   = bA / NA;
    const int A   = bA - b * NA;
    const int tid = threadIdx.x;

    // issue the conf-plane load FIRST: its HBM latency hides under all the
    // metadata/scatter work below.
    const float* base = outp + ((size_t)b * (NA * CH) + (size_t)A * CH) * (NH * NW)
                        + (size_t)q * QPIX;       // base[c*1024 + p], p in [0,256)
    const float conf = base[4 * 1024 + tid];

    __shared__ float s_tx[TBX], s_ty[TBX], s_tw[TBX], s_th[TBX];
    __shared__ unsigned char s_valid[TBX];
    __shared__ int      winner[QPIX];          // last matched box idx per cell (-1 none)
    __shared__ unsigned clsm[QPIX][3];         // 80-bit class union per cell
    __shared__ unsigned clearbits[QPIX / 32];  // 8 words
    __shared__ unsigned objbits[QPIX / 32];
    __shared__ int   objlist[TBX];
    __shared__ float s_part[4];
    __shared__ int   s_trigger;

    // ---- init LDS grids ----
    winner[tid] = -1;
    clsm[tid][0] = 0; clsm[tid][1] = 0; clsm[tid][2] = 0;
    if (tid < QPIX / 32) { clearbits[tid] = 0; objbits[tid] = 0; }

    // ---- phase 1: per-box metadata, all in registers (wave 0 only) ----
    const bool active = tid < TBX;
    int  cell = 0, cls = 0;
    bool match = false, clearb = false, v = false;
    if (active) {
        const float* tg = target + (size_t)b * TBX * 5 + tid * 5;
        float clsf = tg[0];
        float xx = tg[1], yy = tg[2], ww = tg[3], hh = tg[4];
        float gx = xx * NW, gy = yy * NH, gw = ww * NW, gh = hh * NH;
        int gi = (int)gx; gi = min(max(gi, 0), NW - 1);  // trunc == astype(int32)
        int gj = (int)gy; gj = min(max(gj, 0), NH - 1);
        const float AW[NA] = {1.3125f, 3.1875f, 5.03125f, 9.46875f, 11.21875f};
        const float AH[NA] = {1.71875f, 4.0f,   8.09375f, 4.84375f, 10.0f};
        int best = 0; float bi = -1.0f, bw = 0.f, bh = 0.f, iouA = 0.f;
        #pragma unroll
        for (int a = 0; a < NA; ++a) {
            float aw = AW[a], ah = AH[a];
            float inter = fmaxf(fminf(gw, aw) + 1.0f, 0.0f) * fmaxf(fminf(gh, ah) + 1.0f, 0.0f);
            float iou = inter / ((gw + 1.0f) * (gh + 1.0f) + (aw + 1.0f) * (ah + 1.0f) - inter + 1e-16f);
            if (iou > bi) { bi = iou; best = a; bw = aw; bh = ah; }   // first max wins
            if (a == A) iouA = iou;
        }
        cell   = gj * NW + gi;
        match  = (best == A);
        clearb = (iouA > 0.6f) || match;
        cls = (int)clsf; cls = min(max(cls, 0), NCLS - 1);
        // validity = cumprod(x != 0) via one ballot (lanes 0..49 in wave 0)
        unsigned long long m = __ballot(xx != 0.0f);
        v = (((~m) & ((1ULL << (tid + 1)) - 1ULL)) == 0ULL);
        s_valid[tid] = v ? 1 : 0;
        s_tx[tid] = gx - (float)gi;
        s_ty[tid] = gy - (float)gj;
        s_tw[tid] = logf(fmaxf(gw, 1e-8f) / bw);
        s_th[tid] = logf(fmaxf(gh, 1e-8f) / bh);
    }
    __syncthreads();   // LDS-grid init visible

    // ---- phase 2: scatter into LDS grids (registers carried across sync) ----
    if (active && (cell >> 8) == q) {            // cell lies in this block's quarter
        int p = cell & (QPIX - 1);
        if (clearb && v) atomicOr(&clearbits[p >> 5], 1u << (p & 31));
        if (match) {
            atomicMax(&winner[p], tid);          // .set last-write-wins == max box idx
            if (v) {
                atomicOr(&objbits[p >> 5], 1u << (p & 31));
                atomicOr(&clsm[p][cls >> 5], 1u << (cls & 31));
            }
        }
    }
    __syncthreads();

    // ---- phase 3: one pixel per thread; deterministic popcount-rank objlist ----
    float lsum = 0.0f;
    const int p = tid;
    const unsigned ow = objbits[p >> 5];
    const unsigned objb = (ow >> (p & 31)) & 1u;
    const unsigned clrb = (clearbits[p >> 5] >> (p & 31)) & 1u;
    if (objb) {
        int rank = __popc(ow & ((1u << (p & 31)) - 1u));
        for (int k = 0; k < (p >> 5); ++k) rank += __popc(objbits[k]);
        objlist[rank] = p;
    } else if (!clrb) {
        // noobj cell: conf channel only (value already in register)
        lsum += -0.5f * fmaxf(log1pf(-sigm(conf)), -100.0f);  // 0.5*bce(conf,0)
    }
    int nobj = 0;
    #pragma unroll
    for (int k = 0; k < QPIX / 32; ++k) nobj += __popc(objbits[k]);
    __syncthreads();   // objlist visible

    // ---- phase 4: obj cells flattened into nobj*85 parallel work items ----
    const int total = nobj * CH;
    for (int idx = tid; idx < total; idx += 256) {
        int e = idx / CH;               // const-85 division -> magic mul
        int c = idx - e * CH;
        int pc = objlist[e];
        float oc = base[c * 1024 + pc];
        int w = winner[pc];
        bool wv = s_valid[w] != 0;      // invalid winner => targets are 0
        float contrib;
        if (c == 0)      contrib = bce(sigm(oc), wv ? s_tx[w] : 0.0f);
        else if (c == 1) contrib = bce(sigm(oc), wv ? s_ty[w] : 0.0f);
        else if (c == 2) { float d = oc - (wv ? s_tw[w] : 0.0f); contrib = d * d; }
        else if (c == 3) { float d = oc - (wv ? s_th[w] : 0.0f); contrib = d * d; }
        else if (c == 4) contrib = -fmaxf(logf(sigm(oc)), -100.0f);  // bce(conf,1)
        else {
            int cc = c - 5;
            unsigned bit = (clsm[pc][cc >> 5] >> (cc & 31)) & 1u;
            contrib = bce(sigm(oc), bit ? 1.0f : 0.0f);
        }
        lsum += contrib;
    }

    // ---- block reduce: wave64 shuffle + LDS across 4 waves ----
    #pragma unroll
    for (int off = 32; off > 0; off >>= 1)
        lsum += __shfl_down(lsum, off, 64);
    if ((tid & 63) == 0) s_part[tid >> 6] = lsum;
    __syncthreads();

    // ---- EXACT arrive-last (R9-verified: absmax 0.0). ctr zeroed per call by
    // the 1-thread kernel node, so old == nblk-1 is the true last arrival.
    // RMW-only cross-block traffic (R1-proven coherent cross-XCD): publish via
    // atomicExch with return consumed (orders it before the counter RMW);
    // trigger reads partials via atomicAdd(p, 0.0f). Distinct addresses ->
    // no same-address burst (R8 lesson).
    if (tid == 0) {
        float part = s_part[0] + s_part[1] + s_part[2] + s_part[3];
        float oldp = atomicExch(&partials[blk], part);
        asm volatile("" :: "v"(oldp) : "memory");   // consume: vmcnt wait + no reorder
        unsigned old = atomicAdd(ctr, 1u);
        s_trigger = (old == (unsigned)(nblk - 1)) ? 1 : 0;
    }
    __syncthreads();

    // ---- last-arriving block reduces all partials inline (RMW reads);
    // summation order identical to R4's reduce_kernel -> bit-identical out.
    if (s_trigger) {
        float s = 0.0f;
        for (int i = tid; i < nblk; i += 256)
            s += atomicAdd(&partials[i], 0.0f);   // RMW read at coherence point
        #pragma unroll
        for (int off = 32; off > 0; off >>= 1)
            s += __shfl_down(s, off, 64);
        if ((tid & 63) == 0) s_part[tid >> 6] = s;
        __syncthreads();
        if (tid == 0)
            out[0] = (s_part[0] + s_part[1] + s_part[2] + s_part[3]) * inv_nB;
    }
}

extern "C" void kernel_launch(void* const* d_in, const int* in_sizes, int n_in,
                              void* d_out, int out_size, void* d_ws, size_t ws_size,
                              hipStream_t stream) {
    const float* outp   = (const float*)d_in[0];
    const float* target = (const float*)d_in[1];
    float* loss = (float*)d_out;
    int nB = in_sizes[1] / (TBX * 5);   // 64
    int nblk = nB * NA * 4;             // 1280

    // d_ws layout: partials[nblk] f32 | (64B-aligned) u32 arrival counter.
    // partials need no init (every slot atomicExch'd before any read);
    // the counter is zeroed each call by the 1-thread kernel below (NOT
    // hipMemsetAsync: the blit/fill path costs ~11 us fixed — R8/R9).
    char* ws = (char*)d_ws;
    float* partials = (float*)ws;
    size_t off = ((size_t)nblk * sizeof(float) + 63) & ~(size_t)63;
    unsigned* ctr = (unsigned*)(ws + off);

    zero_ctr_kernel<<<1, 1, 0, stream>>>(ctr);
    yolo_loss_kernel<<<nblk, 256, 0, stream>>>(
        outp, target, partials, ctr, loss, nblk, 1.0f / (float)nB);
}

// Round 11
// 23.903 us; speedup vs baseline: 1.2942x; 1.2804x over previous
//
#include <hip/hip_runtime.h>
#include <math.h>

#define NCLS 80
#define NA 5
#define NH 32
#define NW 32
#define TBX 50            // MAX_BOXES
#define CH (5 + NCLS)     // 85 channels per anchor
#define NPIX 1024         // whole 32x32 plane per block

__device__ __forceinline__ float sigm(float z) { return 1.0f / (1.0f + expf(-z)); }

// matches reference: -(t*clip(log p,-100) + (1-t)*clip(log1p(-p),-100))
__device__ __forceinline__ float bce(float p, float t) {
    float lp  = fmaxf(logf(p), -100.0f);
    float l1p = fmaxf(log1pf(-p), -100.0f);
    return -(t * lp + (1.0f - t) * l1p);
}

__global__ __launch_bounds__(1024) void yolo_loss_kernel(
    const float* __restrict__ outp, const float* __restrict__ target,
    float* __restrict__ partials)
{
    const int blk = blockIdx.x;        // b*NA + A
    const int b   = blk / NA;
    const int A   = blk - b * NA;
    const int tid = threadIdx.x;       // 0..1023 == pixel p

    // issue the conf-plane load FIRST: its HBM latency hides under all the
    // metadata/scatter work below.
    const float* base = outp + ((size_t)b * (NA * CH) + (size_t)A * CH) * (NH * NW);
    const float conf = base[4 * 1024 + tid];

    __shared__ float s_tx[TBX], s_ty[TBX], s_tw[TBX], s_th[TBX];
    __shared__ unsigned char s_valid[TBX];
    __shared__ int      winner[NPIX];          // last matched box idx per cell (-1 none)
    __shared__ unsigned clsm[NPIX][3];         // 80-bit class union per cell
    __shared__ unsigned clearbits[NPIX / 32];  // 32 words
    __shared__ unsigned objbits[NPIX / 32];
    __shared__ int   objlist[TBX];
    __shared__ float s_part[16];

    // ---- init LDS grids (one element per thread) ----
    winner[tid] = -1;
    clsm[tid][0] = 0; clsm[tid][1] = 0; clsm[tid][2] = 0;
    if (tid < NPIX / 32) { clearbits[tid] = 0; objbits[tid] = 0; }

    // ---- phase 1: per-box metadata, all in registers (wave 0 only) ----
    const bool active = tid < TBX;
    int  cell = 0, cls = 0;
    bool match = false, clearb = false, v = false;
    if (active) {
        const float* tg = target + (size_t)b * TBX * 5 + tid * 5;
        float clsf = tg[0];
        float xx = tg[1], yy = tg[2], ww = tg[3], hh = tg[4];
        float gx = xx * NW, gy = yy * NH, gw = ww * NW, gh = hh * NH;
        int gi = (int)gx; gi = min(max(gi, 0), NW - 1);  // trunc == astype(int32)
        int gj = (int)gy; gj = min(max(gj, 0), NH - 1);
        const float AW[NA] = {1.3125f, 3.1875f, 5.03125f, 9.46875f, 11.21875f};
        const float AH[NA] = {1.71875f, 4.0f,   8.09375f, 4.84375f, 10.0f};
        int best = 0; float bi = -1.0f, bw = 0.f, bh = 0.f, iouA = 0.f;
        #pragma unroll
        for (int a = 0; a < NA; ++a) {
            float aw = AW[a], ah = AH[a];
            float inter = fmaxf(fminf(gw, aw) + 1.0f, 0.0f) * fmaxf(fminf(gh, ah) + 1.0f, 0.0f);
            float iou = inter / ((gw + 1.0f) * (gh + 1.0f) + (aw + 1.0f) * (ah + 1.0f) - inter + 1e-16f);
            if (iou > bi) { bi = iou; best = a; bw = aw; bh = ah; }   // first max wins
            if (a == A) iouA = iou;
        }
        cell   = gj * NW + gi;
        match  = (best == A);
        clearb = (iouA > 0.6f) || match;
        cls = (int)clsf; cls = min(max(cls, 0), NCLS - 1);
        // validity = cumprod(x != 0) via one ballot (lanes 0..49 in wave 0)
        unsigned long long m = __ballot(xx != 0.0f);
        v = (((~m) & ((1ULL << (tid + 1)) - 1ULL)) == 0ULL);
        s_valid[tid] = v ? 1 : 0;
        s_tx[tid] = gx - (float)gi;
        s_ty[tid] = gy - (float)gj;
        s_tw[tid] = logf(fmaxf(gw, 1e-8f) / bw);
        s_th[tid] = logf(fmaxf(gh, 1e-8f) / bh);
    }
    __syncthreads();   // LDS-grid init visible

    // ---- phase 2: scatter into LDS grids (all cells live in this block) ----
    if (active) {
        int p = cell;
        if (clearb && v) atomicOr(&clearbits[p >> 5], 1u << (p & 31));
        if (match) {
            atomicMax(&winner[p], tid);          // .set last-write-wins == max box idx
            if (v) {
                atomicOr(&objbits[p >> 5], 1u << (p & 31));
                atomicOr(&clsm[p][cls >> 5], 1u << (cls & 31));
            }
        }
    }
    __syncthreads();

    // ---- phase 3: one pixel per thread; deterministic popcount-rank objlist ----
    float lsum = 0.0f;
    const int p = tid;
    const unsigned ow = objbits[p >> 5];
    const unsigned objb = (ow >> (p & 31)) & 1u;
    const unsigned clrb = (clearbits[p >> 5] >> (p & 31)) & 1u;
    if (objb) {
        int rank = __popc(ow & ((1u << (p & 31)) - 1u));
        for (int k = 0; k < (p >> 5); ++k) rank += __popc(objbits[k]);
        objlist[rank] = p;
    } else if (!clrb) {
        // noobj cell: conf channel only (value already in register)
        lsum += -0.5f * fmaxf(log1pf(-sigm(conf)), -100.0f);  // 0.5*bce(conf,0)
    }
    int nobj = 0;
    #pragma unroll
    for (int k = 0; k < NPIX / 32; ++k) nobj += __popc(objbits[k]);
    __syncthreads();   // objlist visible

    // ---- phase 4: obj cells flattened into nobj*85 parallel work items ----
    const int total = nobj * CH;
    for (int idx = tid; idx < total; idx += NPIX) {
        int e = idx / CH;               // const-85 division -> magic mul
        int c = idx - e * CH;
        int pc = objlist[e];
        float oc = base[c * 1024 + pc];
        int w = winner[pc];
        bool wv = s_valid[w] != 0;      // invalid winner => targets are 0
        float contrib;
        if (c == 0)      contrib = bce(sigm(oc), wv ? s_tx[w] : 0.0f);
        else if (c == 1) contrib = bce(sigm(oc), wv ? s_ty[w] : 0.0f);
        else if (c == 2) { float d = oc - (wv ? s_tw[w] : 0.0f); contrib = d * d; }
        else if (c == 3) { float d = oc - (wv ? s_th[w] : 0.0f); contrib = d * d; }
        else if (c == 4) contrib = -fmaxf(logf(sigm(oc)), -100.0f);  // bce(conf,1)
        else {
            int cc = c - 5;
            unsigned bit = (clsm[pc][cc >> 5] >> (cc & 31)) & 1u;
            contrib = bce(sigm(oc), bit ? 1.0f : 0.0f);
        }
        lsum += contrib;
    }

    // ---- block reduce: wave64 shuffle + LDS across 16 waves, store partial ----
    #pragma unroll
    for (int off = 32; off > 0; off >>= 1)
        lsum += __shfl_down(lsum, off, 64);
    if ((tid & 63) == 0) s_part[tid >> 6] = lsum;
    __syncthreads();
    if (tid == 0) {
        float s = 0.0f;
        #pragma unroll
        for (int k = 0; k < 16; ++k) s += s_part[k];
        partials[blk] = s;   // plain store, distinct addresses — no atomic burst
    }
}

__global__ __launch_bounds__(256) void reduce_kernel(
    const float* __restrict__ partials, float* __restrict__ out,
    int n, float inv_nB)
{
    const int tid = threadIdx.x;
    float s = 0.0f;
    for (int i = tid; i < n; i += 256) s += partials[i];
    #pragma unroll
    for (int off = 32; off > 0; off >>= 1)
        s += __shfl_down(s, off, 64);
    __shared__ float sp[4];
    if ((tid & 63) == 0) sp[tid >> 6] = s;
    __syncthreads();
    if (tid == 0)
        out[0] = (sp[0] + sp[1] + sp[2] + sp[3]) * inv_nB;
}

extern "C" void kernel_launch(void* const* d_in, const int* in_sizes, int n_in,
                              void* d_out, int out_size, void* d_ws, size_t ws_size,
                              hipStream_t stream) {
    const float* outp   = (const float*)d_in[0];
    const float* target = (const float*)d_in[1];
    float* loss = (float*)d_out;
    float* partials = (float*)d_ws;     // nB*NA floats, every slot written each call
    int nB = in_sizes[1] / (TBX * 5);   // 64
    int nblk = nB * NA;                 // 320 blocks x 1024 threads
    yolo_loss_kernel<<<nblk, NPIX, 0, stream>>>(outp, target, partials);
    reduce_kernel<<<1, 256, 0, stream>>>(partials, loss, nblk, 1.0f / (float)nB);
}

// Round 12
// 19.237 us; speedup vs baseline: 1.6081x; 1.2426x over previous
//
#include <hip/hip_runtime.h>
#include <math.h>

#define NCLS 80
#define NA 5
#define NH 32
#define NW 32
#define TBX 50            // MAX_BOXES
#define CH (5 + NCLS)     // 85 channels per anchor
#define QPIX 256          // pixels per block (quarter of 32x32)

__device__ __forceinline__ float sigm(float z) { return 1.0f / (1.0f + expf(-z)); }

// matches reference: -(t*clip(log p,-100) + (1-t)*clip(log1p(-p),-100))
__device__ __forceinline__ float bce(float p, float t) {
    float lp  = fmaxf(logf(p), -100.0f);
    float l1p = fmaxf(log1pf(-p), -100.0f);
    return -(t * lp + (1.0f - t) * l1p);
}

// ---- R4 kernel, verbatim (best measured: 19.5 us total, absmax 0.0) ----
__global__ __launch_bounds__(256) void yolo_loss_kernel(
    const float* __restrict__ outp, const float* __restrict__ target,
    float* __restrict__ partials)
{
    const int blk = blockIdx.x;        // ((b*NA)+A)*4 + q
    const int q   = blk & 3;
    const int bA  = blk >> 2;
    const int b   = bA / NA;
    const int A   = bA - b * NA;
    const int tid = threadIdx.x;

    // issue the conf-plane load FIRST: its HBM latency hides under all the
    // metadata/scatter work below.
    const float* base = outp + ((size_t)b * (NA * CH) + (size_t)A * CH) * (NH * NW)
                        + (size_t)q * QPIX;       // base[c*1024 + p], p in [0,256)
    const float conf = base[4 * 1024 + tid];

    __shared__ float s_tx[TBX], s_ty[TBX], s_tw[TBX], s_th[TBX];
    __shared__ unsigned char s_valid[TBX];
    __shared__ int      winner[QPIX];          // last matched box idx per cell (-1 none)
    __shared__ unsigned clsm[QPIX][3];         // 80-bit class union per cell
    __shared__ unsigned clearbits[QPIX / 32];  // 8 words
    __shared__ unsigned objbits[QPIX / 32];
    __shared__ int   objlist[TBX];
    __shared__ float s_part[4];

    // ---- init LDS grids ----
    winner[tid] = -1;
    clsm[tid][0] = 0; clsm[tid][1] = 0; clsm[tid][2] = 0;
    if (tid < QPIX / 32) { clearbits[tid] = 0; objbits[tid] = 0; }

    // ---- phase 1: per-box metadata, all in registers (wave 0 only) ----
    const bool active = tid < TBX;
    int  cell = 0, cls = 0;
    bool match = false, clearb = false, v = false;
    if (active) {
        const float* tg = target + (size_t)b * TBX * 5 + tid * 5;
        float clsf = tg[0];
        float xx = tg[1], yy = tg[2], ww = tg[3], hh = tg[4];
        float gx = xx * NW, gy = yy * NH, gw = ww * NW, gh = hh * NH;
        int gi = (int)gx; gi = min(max(gi, 0), NW - 1);  // trunc == astype(int32)
        int gj = (int)gy; gj = min(max(gj, 0), NH - 1);
        const float AW[NA] = {1.3125f, 3.1875f, 5.03125f, 9.46875f, 11.21875f};
        const float AH[NA] = {1.71875f, 4.0f,   8.09375f, 4.84375f, 10.0f};
        int best = 0; float bi = -1.0f, bw = 0.f, bh = 0.f, iouA = 0.f;
        #pragma unroll
        for (int a = 0; a < NA; ++a) {
            float aw = AW[a], ah = AH[a];
            float inter = fmaxf(fminf(gw, aw) + 1.0f, 0.0f) * fmaxf(fminf(gh, ah) + 1.0f, 0.0f);
            float iou = inter / ((gw + 1.0f) * (gh + 1.0f) + (aw + 1.0f) * (ah + 1.0f) - inter + 1e-16f);
            if (iou > bi) { bi = iou; best = a; bw = aw; bh = ah; }   // first max wins
            if (a == A) iouA = iou;
        }
        cell   = gj * NW + gi;
        match  = (best == A);
        clearb = (iouA > 0.6f) || match;
        cls = (int)clsf; cls = min(max(cls, 0), NCLS - 1);
        // validity = cumprod(x != 0) via one ballot (lanes 0..49 in wave 0)
        unsigned long long m = __ballot(xx != 0.0f);
        v = (((~m) & ((1ULL << (tid + 1)) - 1ULL)) == 0ULL);
        s_valid[tid] = v ? 1 : 0;
        s_tx[tid] = gx - (float)gi;
        s_ty[tid] = gy - (float)gj;
        s_tw[tid] = logf(fmaxf(gw, 1e-8f) / bw);
        s_th[tid] = logf(fmaxf(gh, 1e-8f) / bh);
    }
    __syncthreads();   // LDS-grid init visible

    // ---- phase 2: scatter into LDS grids (registers carried across sync) ----
    if (active && (cell >> 8) == q) {            // cell lies in this block's quarter
        int p = cell & (QPIX - 1);
        if (clearb && v) atomicOr(&clearbits[p >> 5], 1u << (p & 31));
        if (match) {
            atomicMax(&winner[p], tid);          // .set last-write-wins == max box idx
            if (v) {
                atomicOr(&objbits[p >> 5], 1u << (p & 31));
                atomicOr(&clsm[p][cls >> 5], 1u << (cls & 31));
            }
        }
    }
    __syncthreads();

    // ---- phase 3: one pixel per thread; deterministic popcount-rank objlist ----
    float lsum = 0.0f;
    const int p = tid;
    const unsigned ow = objbits[p >> 5];
    const unsigned objb = (ow >> (p & 31)) & 1u;
    const unsigned clrb = (clearbits[p >> 5] >> (p & 31)) & 1u;
    if (objb) {
        int rank = __popc(ow & ((1u << (p & 31)) - 1u));
        for (int k = 0; k < (p >> 5); ++k) rank += __popc(objbits[k]);
        objlist[rank] = p;
    } else if (!clrb) {
        // noobj cell: conf channel only (value already in register)
        lsum += -0.5f * fmaxf(log1pf(-sigm(conf)), -100.0f);  // 0.5*bce(conf,0)
    }
    int nobj = 0;
    #pragma unroll
    for (int k = 0; k < QPIX / 32; ++k) nobj += __popc(objbits[k]);
    __syncthreads();   // objlist visible

    // ---- phase 4: obj cells flattened into nobj*85 parallel work items ----
    const int total = nobj * CH;
    for (int idx = tid; idx < total; idx += 256) {
        int e = idx / CH;               // const-85 division -> magic mul
        int c = idx - e * CH;
        int pc = objlist[e];
        float oc = base[c * 1024 + pc];
        int w = winner[pc];
        bool wv = s_valid[w] != 0;      // invalid winner => targets are 0
        float contrib;
        if (c == 0)      contrib = bce(sigm(oc), wv ? s_tx[w] : 0.0f);
        else if (c == 1) contrib = bce(sigm(oc), wv ? s_ty[w] : 0.0f);
        else if (c == 2) { float d = oc - (wv ? s_tw[w] : 0.0f); contrib = d * d; }
        else if (c == 3) { float d = oc - (wv ? s_th[w] : 0.0f); contrib = d * d; }
        else if (c == 4) contrib = -fmaxf(logf(sigm(oc)), -100.0f);  // bce(conf,1)
        else {
            int cc = c - 5;
            unsigned bit = (clsm[pc][cc >> 5] >> (cc & 31)) & 1u;
            contrib = bce(sigm(oc), bit ? 1.0f : 0.0f);
        }
        lsum += contrib;
    }

    // ---- reduce: wave64 shuffle + LDS across 4 waves, store partial ----
    #pragma unroll
    for (int off = 32; off > 0; off >>= 1)
        lsum += __shfl_down(lsum, off, 64);
    if ((tid & 63) == 0) s_part[tid >> 6] = lsum;
    __syncthreads();
    if (tid == 0)
        partials[blk] = s_part[0] + s_part[1] + s_part[2] + s_part[3];
}

// Single-wave reduce: no barrier, no LDS, float4 loads (1280/4/64 = 5 per lane).
__global__ __launch_bounds__(64) void reduce_kernel(
    const float* __restrict__ partials, float* __restrict__ out,
    int n, float inv_nB)
{
    const int lane = threadIdx.x;
    float s = 0.0f;
    const float4* p4 = (const float4*)partials;
    for (int i = lane; i < n / 4; i += 64) {
        float4 v = p4[i];
        s += v.x + v.y + v.z + v.w;
    }
    #pragma unroll
    for (int off = 32; off > 0; off >>= 1)
        s += __shfl_down(s, off, 64);
    if (lane == 0)
        out[0] = s * inv_nB;
}

extern "C" void kernel_launch(void* const* d_in, const int* in_sizes, int n_in,
                              void* d_out, int out_size, void* d_ws, size_t ws_size,
                              hipStream_t stream) {
    const float* outp   = (const float*)d_in[0];
    const float* target = (const float*)d_in[1];
    float* loss = (float*)d_out;
    float* partials = (float*)d_ws;     // nB*NA*4 floats, every slot written each call
    int nB = in_sizes[1] / (TBX * 5);   // 64
    int nblk = nB * NA * 4;             // 1280 (divisible by 4 for float4 reduce)
    yolo_loss_kernel<<<nblk, 256, 0, stream>>>(outp, target, partials);
    reduce_kernel<<<1, 64, 0, stream>>>(partials, loss, nblk, 1.0f / (float)nB);
}